// Round 1
// baseline (102.201 us; speedup 1.0000x reference)
//
#include <hip/hip_runtime.h>

// EulerToAffine: per row, angles (ax,ay,az) + translation t -> 3x4 [R|t], R = Rx*Ry*Rz.
// Expanded:
//   R00 = cy*cz          R01 = -cy*sz          R02 = sy
//   R10 = cx*sz+sx*sy*cz R11 = cx*cz-sx*sy*sz  R12 = -sx*cy
//   R20 = sx*sz-cx*sy*cz R21 = sx*cz+cx*sy*sz  R22 = cx*cy
// Output row layout (reshape of concat([R, t], axis=2)): R00 R01 R02 t0 | R10 R11 R12 t1 | R20 R21 R22 t2

__device__ __forceinline__ void euler_row(float ax, float ay, float az,
                                          float tx, float ty, float tz,
                                          float4& o0, float4& o1, float4& o2) {
    float sx, cx, sy, cy, sz, cz;
    __sincosf(ax, &sx, &cx);
    __sincosf(ay, &sy, &cy);
    __sincosf(az, &sz, &cz);

    float sycz = sy * cz;
    float sysz = sy * sz;

    o0.x = cy * cz;
    o0.y = -cy * sz;
    o0.z = sy;
    o0.w = tx;

    o1.x = fmaf(sx, sycz, cx * sz);
    o1.y = fmaf(-sx, sysz, cx * cz);
    o1.z = -sx * cy;
    o1.w = ty;

    o2.x = fmaf(-cx, sycz, sx * sz);
    o2.y = fmaf(cx, sysz, sx * cz);
    o2.z = cx * cy;
    o2.w = tz;
}

// One thread handles TWO rows: 2 rows * 6 f32 = 48 B = 3 x float4 (16B-aligned),
// output 2 rows * 12 f32 = 96 B = 6 x float4. Fully vectorized, no LDS needed.
__global__ __launch_bounds__(256) void EulerToAffine_74208444940704_kernel(
        const float* __restrict__ in, float* __restrict__ out, int npairs) {
    int tid = blockIdx.x * blockDim.x + threadIdx.x;
    int stride = gridDim.x * blockDim.x;
    for (int i = tid; i < npairs; i += stride) {
        const float4* ip = reinterpret_cast<const float4*>(in) + (size_t)i * 3;
        float4 a = ip[0];
        float4 b = ip[1];
        float4 c = ip[2];

        float4 o0, o1, o2, o3, o4, o5;
        // row 2i:   ax=a.x ay=a.y az=a.z  t=(a.w, b.x, b.y)
        euler_row(a.x, a.y, a.z, a.w, b.x, b.y, o0, o1, o2);
        // row 2i+1: ax=b.z ay=b.w az=c.x  t=(c.y, c.z, c.w)
        euler_row(b.z, b.w, c.x, c.y, c.z, c.w, o3, o4, o5);

        float4* op = reinterpret_cast<float4*>(out) + (size_t)i * 6;
        op[0] = o0; op[1] = o1; op[2] = o2;
        op[3] = o3; op[4] = o4; op[5] = o5;
    }
}

extern "C" void kernel_launch(void* const* d_in, const int* in_sizes, int n_in,
                              void* d_out, int out_size, void* d_ws, size_t ws_size,
                              hipStream_t stream) {
    const float* in = (const float*)d_in[0];
    float* out = (float*)d_out;
    int nrows = in_sizes[0] / 6;          // 4194304
    int npairs = nrows / 2;               // 2097152 (nrows is even)

    const int block = 256;
    int grid = (npairs + block - 1) / block;
    const int max_grid = 2048;            // 256 CU x 8 blocks, grid-stride the rest
    if (grid > max_grid) grid = max_grid;

    EulerToAffine_74208444940704_kernel<<<grid, block, 0, stream>>>(in, out, npairs);
}

// Round 2
// 54.040 us; speedup vs baseline: 1.8912x; 1.8912x over previous
//
#include <hip/hip_runtime.h>

// EulerToAffine: per row, angles (ax,ay,az) + translation t -> 3x4 [R|t], R = Rx*Ry*Rz.
//   R00 = cy*cz          R01 = -cy*sz          R02 = sy
//   R10 = cx*sz+sx*sy*cz R11 = cx*cz-sx*sy*sz  R12 = -sx*cy
//   R20 = sx*sz-cx*sy*cz R21 = sx*cz+cx*sy*sz  R22 = cx*cy
// Output row: R00 R01 R02 t0 | R10 R11 R12 t1 | R20 R21 R22 t2
//
// R1 post-mortem: direct strided float4 access (48B/96B lane stride) ran at
// 2.96 TB/s effective -- partial-line stores likely triggered L2
// read-for-ownership on the 201MB output. This version stages chunks through
// LDS so every global load/store is lane-contiguous float4 (full-line,
// fill-kernel-like).

__device__ __forceinline__ void euler_row(float ax, float ay, float az,
                                          float tx, float ty, float tz,
                                          float4& o0, float4& o1, float4& o2) {
    float sx, cx, sy, cy, sz, cz;
    __sincosf(ax, &sx, &cx);
    __sincosf(ay, &sy, &cy);
    __sincosf(az, &sz, &cz);

    float sycz = sy * cz;
    float sysz = sy * sz;

    o0.x = cy * cz;
    o0.y = -cy * sz;
    o0.z = sy;
    o0.w = tx;

    o1.x = fmaf(sx, sycz, cx * sz);
    o1.y = fmaf(-sx, sysz, cx * cz);
    o1.z = -sx * cy;
    o1.w = ty;

    o2.x = fmaf(-cx, sycz, sx * sz);
    o2.y = fmaf(cx, sysz, sx * cz);
    o2.z = cx * cy;
    o2.w = tz;
}

// Chunk = 512 rows. in: 512*6 f32 = 768 float4 (12 KB). out: 1536 float4 (24 KB).
// 256 threads: each stages 3 in-float4 + 6 out-float4 lane-contiguously and
// computes 2 rows (pair) from LDS.
__global__ __launch_bounds__(256) void EulerToAffine_74208444940704_kernel(
        const float4* __restrict__ in4, float4* __restrict__ out4, int nchunks) {
    __shared__ float4 s_in[768];
    __shared__ float4 s_out[1536];
    const int t = threadIdx.x;

    for (int c = blockIdx.x; c < nchunks; c += gridDim.x) {
        const size_t ib = (size_t)c * 768;
        s_in[t]       = in4[ib + t];
        s_in[t + 256] = in4[ib + t + 256];
        s_in[t + 512] = in4[ib + t + 512];
        __syncthreads();

        // thread t: rows 2t, 2t+1 of the chunk = float4 slots 3t..3t+2
        const float4* sp = s_in + t * 3;
        float4 a = sp[0];
        float4 b = sp[1];
        float4 cc = sp[2];

        float4 o0, o1, o2, o3, o4, o5;
        euler_row(a.x, a.y, a.z, a.w, b.x, b.y, o0, o1, o2);
        euler_row(b.z, b.w, cc.x, cc.y, cc.z, cc.w, o3, o4, o5);

        float4* op = s_out + t * 6;
        op[0] = o0; op[1] = o1; op[2] = o2;
        op[3] = o3; op[4] = o4; op[5] = o5;
        __syncthreads();

        const size_t ob = (size_t)c * 1536;
        out4[ob + t]        = s_out[t];
        out4[ob + t + 256]  = s_out[t + 256];
        out4[ob + t + 512]  = s_out[t + 512];
        out4[ob + t + 768]  = s_out[t + 768];
        out4[ob + t + 1024] = s_out[t + 1024];
        out4[ob + t + 1280] = s_out[t + 1280];
        __syncthreads();   // protect s_in/s_out before next iteration overwrites
    }
}

// Fallback for tail rows (not hit at N=4194304, which is 8192 full chunks).
__global__ __launch_bounds__(256) void EulerToAffine_tail_kernel(
        const float* __restrict__ in, float* __restrict__ out,
        int row0, int nrows) {
    int r = row0 + blockIdx.x * blockDim.x + threadIdx.x;
    if (r >= nrows) return;
    const float* ip = in + (size_t)r * 6;
    float4 o0, o1, o2;
    euler_row(ip[0], ip[1], ip[2], ip[3], ip[4], ip[5], o0, o1, o2);
    float* op = out + (size_t)r * 12;
    op[0] = o0.x; op[1] = o0.y; op[2]  = o0.z; op[3]  = o0.w;
    op[4] = o1.x; op[5] = o1.y; op[6]  = o1.z; op[7]  = o1.w;
    op[8] = o2.x; op[9] = o2.y; op[10] = o2.z; op[11] = o2.w;
}

extern "C" void kernel_launch(void* const* d_in, const int* in_sizes, int n_in,
                              void* d_out, int out_size, void* d_ws, size_t ws_size,
                              hipStream_t stream) {
    const float* in = (const float*)d_in[0];
    float* out = (float*)d_out;
    int nrows = in_sizes[0] / 6;          // 4194304
    int nchunks = nrows / 512;            // 8192 full chunks

    if (nchunks > 0) {
        int grid = nchunks < 2048 ? nchunks : 2048;  // grid-stride the rest
        EulerToAffine_74208444940704_kernel<<<grid, 256, 0, stream>>>(
            (const float4*)in, (float4*)out, nchunks);
    }
    int done = nchunks * 512;
    int rem = nrows - done;
    if (rem > 0) {
        EulerToAffine_tail_kernel<<<(rem + 255) / 256, 256, 0, stream>>>(
            in, out, done, nrows);
    }
}